// Round 1
// baseline (150.543 us; speedup 1.0000x reference)
//
#include <hip/hip_runtime.h>
#include <hip/hip_bf16.h>
#include <math.h>

#define NBINS 10
#define BIN_SCALE 9.9999f   // BINS - 1e-4, matches reference

// ws layout (floats): [0..9] = per-bin sum of bce, [10..19] = per-bin count

__global__ __launch_bounds__(64) void ghm_zero_ws(float* ws) {
    if (threadIdx.x < 2 * NBINS) ws[threadIdx.x] = 0.0f;
}

__device__ __forceinline__ void ghm_accum(float xx, float tt, float* s, float* c) {
    float ax = fabsf(xx);
    float e  = __expf(-ax);                        // exp(-|x|) in (0,1], no overflow
    float sp = __builtin_amdgcn_rcpf(1.0f + e);    // sigmoid(|x|), v_rcp_f32 ~1ulp
    float sg = (xx >= 0.0f) ? sp : 1.0f - sp;      // sigmoid(x), stable
    float g  = fabsf(sg - tt);                     // gradient magnitude
    int idx  = (int)(g * BIN_SCALE);               // g>=0 so trunc == floor
    idx = idx > (NBINS - 1) ? (NBINS - 1) : idx;
    // stable BCE-with-logits: max(x,0) - x*t + log1p(exp(-|x|))
    float bce = fmaxf(xx, 0.0f) - xx * tt + __logf(1.0f + e);
    #pragma unroll
    for (int j = 0; j < NBINS; ++j) {
        bool m = (idx == j);
        s[j] += m ? bce : 0.0f;
        c[j] += m ? 1.0f : 0.0f;                   // integer-valued float, exact
    }
}

__global__ __launch_bounds__(256) void ghm_pass1(const float4* __restrict__ x,
                                                 const float4* __restrict__ t,
                                                 float* __restrict__ ws, int n4) {
    float s[NBINS], c[NBINS];
    #pragma unroll
    for (int j = 0; j < NBINS; ++j) { s[j] = 0.0f; c[j] = 0.0f; }

    int tid    = blockIdx.x * blockDim.x + threadIdx.x;
    int stride = gridDim.x * blockDim.x;
    for (int i = tid; i < n4; i += stride) {
        float4 xv = x[i];
        float4 tv = t[i];
        ghm_accum(xv.x, tv.x, s, c);
        ghm_accum(xv.y, tv.y, s, c);
        ghm_accum(xv.z, tv.z, s, c);
        ghm_accum(xv.w, tv.w, s, c);
    }

    // wave-level butterfly reduce (wave = 64 on gfx950)
    #pragma unroll
    for (int j = 0; j < NBINS; ++j) {
        for (int off = 32; off > 0; off >>= 1) {
            s[j] += __shfl_down(s[j], off, 64);
            c[j] += __shfl_down(c[j], off, 64);
        }
    }

    __shared__ float sm[4 * 2 * NBINS];  // 4 waves x (10 sums + 10 counts)
    int lane = threadIdx.x & 63;
    int wave = threadIdx.x >> 6;
    if (lane == 0) {
        #pragma unroll
        for (int j = 0; j < NBINS; ++j) {
            sm[wave * 2 * NBINS + j]         = s[j];
            sm[wave * 2 * NBINS + NBINS + j] = c[j];
        }
    }
    __syncthreads();
    if (threadIdx.x < 2 * NBINS) {
        float v = sm[threadIdx.x] + sm[2 * NBINS + threadIdx.x]
                + sm[4 * NBINS + threadIdx.x] + sm[6 * NBINS + threadIdx.x];
        atomicAdd(&ws[threadIdx.x], v);  // device-scope, 20 atomics/block
    }
}

__global__ __launch_bounds__(64) void ghm_finalize(const float* __restrict__ ws,
                                                   float* __restrict__ out) {
    if (threadIdx.x == 0) {
        float ne = 0.0f;
        #pragma unroll
        for (int j = 0; j < NBINS; ++j) ne += (ws[NBINS + j] > 0.0f) ? 1.0f : 0.0f;
        float tot = 0.0f;
        #pragma unroll
        for (int j = 0; j < NBINS; ++j)
            tot += ws[j] / fmaxf(ws[NBINS + j] * ne, 1e-4f);
        // mean(w*bce) = sum_b S_b / gd_b  (the N's cancel)
        out[0] = tot;
    }
}

extern "C" void kernel_launch(void* const* d_in, const int* in_sizes, int n_in,
                              void* d_out, int out_size, void* d_ws, size_t ws_size,
                              hipStream_t stream) {
    const float4* x = (const float4*)d_in[0];
    const float4* t = (const float4*)d_in[1];
    float* ws  = (float*)d_ws;
    float* out = (float*)d_out;
    int n  = in_sizes[0];        // 4096*4096 = 16,777,216 (divisible by 4)
    int n4 = n >> 2;

    ghm_zero_ws<<<1, 64, 0, stream>>>(ws);
    // 1024 blocks x 256 thr = 16 waves/CU across 256 CUs; 16 float4 iters/thread
    ghm_pass1<<<1024, 256, 0, stream>>>(x, t, ws, n4);
    ghm_finalize<<<1, 64, 0, stream>>>(ws, out);
}

// Round 2
// 146.555 us; speedup vs baseline: 1.0272x; 1.0272x over previous
//
#include <hip/hip_runtime.h>
#include <hip/hip_bf16.h>
#include <math.h>

#define NBINS 10
#define BIN_SCALE 9.9999f      // BINS - 1e-4, matches reference
#define COPIES 16              // histogram replicas per wave (lane & 15)
#define HSTRIDE 11             // u64 stride per replica; 11 odd -> spreads bank pairs
#define NWAVES 4
#define FIXSCALE 4096.0f       // 2^12 fixed-point for bce sums
#define CNT_SHIFT 39           // bits [63:39] = count, [38:0] = fixed-point sum

typedef unsigned long long u64;

// ws layout: parts[block][bin] as u64, written unconditionally by every block
// (no zero-init of ws needed; harness poison is overwritten).

__global__ __launch_bounds__(256) void ghm_pass1(const float4* __restrict__ x,
                                                 const float4* __restrict__ t,
                                                 u64* __restrict__ parts, int n4) {
    __shared__ u64 hist[NWAVES * COPIES * HSTRIDE];   // 704 u64 = 5632 B
    for (int i = threadIdx.x; i < NWAVES * COPIES * HSTRIDE; i += 256) hist[i] = 0ull;
    __syncthreads();

    const int lane = threadIdx.x & 63;
    const int wave = threadIdx.x >> 6;
    u64* my = &hist[(wave * COPIES + (lane & (COPIES - 1))) * HSTRIDE];

    int tid    = blockIdx.x * blockDim.x + threadIdx.x;
    int stride = gridDim.x * blockDim.x;
    for (int i = tid; i < n4; i += stride) {
        float4 xv = x[i];
        float4 tv = t[i];
        float xs[4] = {xv.x, xv.y, xv.z, xv.w};
        float ts[4] = {tv.x, tv.y, tv.z, tv.w};
        #pragma unroll
        for (int k = 0; k < 4; ++k) {
            float xx = xs[k], tt = ts[k];
            float ax = fabsf(xx);
            float e  = __expf(-ax);                      // exp(-|x|) in (0,1]
            float sp = __builtin_amdgcn_rcpf(1.0f + e);  // sigmoid(|x|)
            float sg = (xx >= 0.0f) ? sp : 1.0f - sp;    // sigmoid(x), stable
            float g  = fabsf(sg - tt);
            int idx  = (int)(g * BIN_SCALE);             // g>=0 -> trunc == floor
            idx = idx > NBINS - 1 ? NBINS - 1 : idx;
            // stable BCE-with-logits: max(x,0) - x*t + log1p(exp(-|x|))
            float bce = fmaxf(xx, 0.0f) - xx * tt + __logf(1.0f + e);
            u64 inc = ((u64)1 << CNT_SHIFT)
                    | (u64)(unsigned)(bce * FIXSCALE + 0.5f);
            atomicAdd(&my[idx], inc);                    // ds_add_u64, fire-and-forget
        }
    }
    __syncthreads();

    // block partial: thread b sums the 64 replicas for bin b, writes its slot
    if (threadIdx.x < NBINS) {
        u64 a = 0;
        for (int c = 0; c < NWAVES * COPIES; ++c) a += hist[c * HSTRIDE + threadIdx.x];
        parts[blockIdx.x * NBINS + threadIdx.x] = a;
    }
}

__global__ __launch_bounds__(64) void ghm_finalize(const u64* __restrict__ parts,
                                                   float* __restrict__ out, int nblocks) {
    u64 acc[NBINS];
    #pragma unroll
    for (int b = 0; b < NBINS; ++b) acc[b] = 0ull;
    for (int blk = threadIdx.x; blk < nblocks; blk += 64) {
        #pragma unroll
        for (int b = 0; b < NBINS; ++b) acc[b] += parts[blk * NBINS + b];
    }
    #pragma unroll
    for (int b = 0; b < NBINS; ++b)
        for (int off = 32; off; off >>= 1)
            acc[b] += __shfl_down(acc[b], off, 64);

    if (threadIdx.x == 0) {
        const u64 smask = ((u64)1 << CNT_SHIFT) - 1;
        float cnt[NBINS], sum[NBINS];
        float ne = 0.0f;
        #pragma unroll
        for (int b = 0; b < NBINS; ++b) {
            cnt[b] = (float)(acc[b] >> CNT_SHIFT);
            sum[b] = (float)((double)(acc[b] & smask) / (double)FIXSCALE);
            ne += (cnt[b] > 0.0f) ? 1.0f : 0.0f;
        }
        float tot = 0.0f;
        #pragma unroll
        for (int b = 0; b < NBINS; ++b)
            tot += sum[b] / fmaxf(cnt[b] * ne, 1e-4f);
        // mean(w*bce) = sum_b S_b / gd_b  (the N's cancel)
        out[0] = tot;
    }
}

extern "C" void kernel_launch(void* const* d_in, const int* in_sizes, int n_in,
                              void* d_out, int out_size, void* d_ws, size_t ws_size,
                              hipStream_t stream) {
    const float4* x = (const float4*)d_in[0];
    const float4* t = (const float4*)d_in[1];
    u64*  parts = (u64*)d_ws;
    float* out  = (float*)d_out;
    int n  = in_sizes[0];         // 4096*4096, divisible by 4
    int n4 = n >> 2;

    int nb = 1024;                // 4 blocks/CU, 16 waves/CU
    size_t need = (size_t)nb * NBINS * sizeof(u64);   // 80 KB of ws
    if (ws_size < need) {
        nb = (int)(ws_size / (NBINS * sizeof(u64)));
        if (nb < 1) nb = 1;       // grid-stride keeps correctness at any nb
    }

    ghm_pass1<<<nb, 256, 0, stream>>>(x, t, parts, n4);
    ghm_finalize<<<1, 64, 0, stream>>>(parts, out, nb);
}

// Round 3
// 146.531 us; speedup vs baseline: 1.0274x; 1.0002x over previous
//
#include <hip/hip_runtime.h>
#include <hip/hip_bf16.h>
#include <math.h>

#define NBINS 10
#define BIN_SCALE 9.9999f      // BINS - 1e-4, matches reference
#define COPIES 32              // histogram replicas per wave (lane & 31): 2 lanes/replica
#define HSTRIDE 11             // u64 stride per replica; (11r mod 16) covers all bank-pairs
#define NWAVES 4
#define NREP (NWAVES * COPIES) // 128 replicas per block
#define FIXSCALE 4096.0f       // 2^12 fixed-point for bce sums
#define CNT_SHIFT 39           // bits [63:39] = count, [38:0] = fixed-point sum

typedef unsigned long long u64;

__device__ __forceinline__ void ghm_accum4(float4 xv, float4 tv, u64* my) {
    float xs[4] = {xv.x, xv.y, xv.z, xv.w};
    float ts[4] = {tv.x, tv.y, tv.z, tv.w};
    #pragma unroll
    for (int k = 0; k < 4; ++k) {
        float xx = xs[k], tt = ts[k];
        float ax = fabsf(xx);
        float e  = __expf(-ax);                      // exp(-|x|) in (0,1]
        float sp = __builtin_amdgcn_rcpf(1.0f + e);  // sigmoid(|x|)
        float sg = (xx >= 0.0f) ? sp : 1.0f - sp;    // sigmoid(x), stable
        float g  = fabsf(sg - tt);
        int idx  = (int)(g * BIN_SCALE);             // g>=0 -> trunc == floor
        idx = idx > NBINS - 1 ? NBINS - 1 : idx;
        // stable BCE-with-logits: max(x,0) - x*t + log1p(exp(-|x|))
        float bce = fmaxf(xx, 0.0f) - xx * tt + __logf(1.0f + e);
        u64 inc = ((u64)1 << CNT_SHIFT)
                | (u64)(unsigned)(bce * FIXSCALE + 0.5f);
        atomicAdd(&my[idx], inc);                    // ds_add_u64, fire-and-forget
    }
}

// 8 blocks/CU x 4 waves = 32 waves/CU -> 100% occupancy (VGPR~32 <= 64 cap)
__global__ __launch_bounds__(256, 8) void ghm_pass1(const float4* __restrict__ x,
                                                    const float4* __restrict__ t,
                                                    u64* __restrict__ parts, int n4) {
    __shared__ u64 hist[NREP * HSTRIDE];             // 1408 u64 = 11264 B
    for (int i = threadIdx.x; i < NREP * HSTRIDE; i += 256) hist[i] = 0ull;
    __syncthreads();

    const int lane = threadIdx.x & 63;
    const int wave = threadIdx.x >> 6;
    u64* my = &hist[(wave * COPIES + (lane & (COPIES - 1))) * HSTRIDE];

    const int T   = gridDim.x * blockDim.x;
    const int tid = blockIdx.x * blockDim.x + threadIdx.x;

    int i = tid;
    // unroll x2: issue all 4 global loads before computing (4-deep MLP/thread)
    for (; i + T < n4; i += 2 * T) {
        float4 xa = x[i];
        float4 xb = x[i + T];
        float4 ta = t[i];
        float4 tb = t[i + T];
        ghm_accum4(xa, ta, my);
        ghm_accum4(xb, tb, my);
    }
    for (; i < n4; i += T) {
        float4 xa = x[i];
        float4 ta = t[i];
        ghm_accum4(xa, ta, my);
    }
    __syncthreads();

    // fold 128 replicas -> 8 groups of 16, then 8 -> 1
    if (threadIdx.x < 128) {
        int b = threadIdx.x & 15;                    // 16-slot layout, 10 valid
        int grp = threadIdx.x >> 4;                  // 8 groups x 16 replicas
        if (b < NBINS) {
            u64 a = 0;
            int r0 = grp * 16;
            #pragma unroll
            for (int r = 0; r < 16; ++r) a += hist[(r0 + r) * HSTRIDE + b];
            hist[r0 * HSTRIDE + b] = a;              // disjoint (grp,b) slots
        }
    }
    __syncthreads();
    if (threadIdx.x < NBINS) {
        u64 a = 0;
        #pragma unroll
        for (int g = 0; g < 8; ++g) a += hist[(g * 16) * HSTRIDE + threadIdx.x];
        parts[blockIdx.x * NBINS + threadIdx.x] = a; // every slot written: no ws zero-init
    }
}

__global__ __launch_bounds__(256) void ghm_finalize(const u64* __restrict__ parts,
                                                    float* __restrict__ out, int nblocks) {
    u64 acc[NBINS];
    #pragma unroll
    for (int b = 0; b < NBINS; ++b) acc[b] = 0ull;
    for (int blk = threadIdx.x; blk < nblocks; blk += 256) {
        #pragma unroll
        for (int b = 0; b < NBINS; ++b) acc[b] += parts[blk * NBINS + b];
    }
    // wave butterfly then cross-wave via LDS
    #pragma unroll
    for (int b = 0; b < NBINS; ++b)
        for (int off = 32; off; off >>= 1)
            acc[b] += __shfl_down(acc[b], off, 64);

    __shared__ u64 sm[4 * NBINS];
    int lane = threadIdx.x & 63;
    int wave = threadIdx.x >> 6;
    if (lane == 0) {
        #pragma unroll
        for (int b = 0; b < NBINS; ++b) sm[wave * NBINS + b] = acc[b];
    }
    __syncthreads();

    if (threadIdx.x == 0) {
        const u64 smask = ((u64)1 << CNT_SHIFT) - 1;
        float ne = 0.0f;
        float cnt[NBINS], sum[NBINS];
        #pragma unroll
        for (int b = 0; b < NBINS; ++b) {
            u64 a = sm[b] + sm[NBINS + b] + sm[2 * NBINS + b] + sm[3 * NBINS + b];
            cnt[b] = (float)(a >> CNT_SHIFT);
            sum[b] = (float)((double)(a & smask) / (double)FIXSCALE);
            ne += (cnt[b] > 0.0f) ? 1.0f : 0.0f;
        }
        float tot = 0.0f;
        #pragma unroll
        for (int b = 0; b < NBINS; ++b)
            tot += sum[b] / fmaxf(cnt[b] * ne, 1e-4f);
        // mean(w*bce) = sum_b S_b / gd_b  (the N's cancel)
        out[0] = tot;
    }
}

extern "C" void kernel_launch(void* const* d_in, const int* in_sizes, int n_in,
                              void* d_out, int out_size, void* d_ws, size_t ws_size,
                              hipStream_t stream) {
    const float4* x = (const float4*)d_in[0];
    const float4* t = (const float4*)d_in[1];
    u64*  parts = (u64*)d_ws;
    float* out  = (float*)d_out;
    int n  = in_sizes[0];         // 4096*4096, divisible by 4
    int n4 = n >> 2;

    int nb = 2048;                // 8 blocks/CU -> 32 waves/CU (100% occupancy)
    size_t need = (size_t)nb * NBINS * sizeof(u64);   // 160 KB of ws
    if (ws_size < need) {
        nb = (int)(ws_size / (NBINS * sizeof(u64)));
        if (nb < 1) nb = 1;       // grid-stride keeps correctness at any nb
    }

    ghm_pass1<<<nb, 256, 0, stream>>>(x, t, parts, n4);
    ghm_finalize<<<1, 256, 0, stream>>>(parts, out, nb);
}